// Round 7
// baseline (326.216 us; speedup 1.0000x reference)
//
#include <hip/hip_runtime.h>
#include <cmath>
#include <cstdint>
#include <cstddef>

typedef __bf16 bf16_t;
typedef _Float16 f16_t;
typedef __bf16 bf16x8 __attribute__((ext_vector_type(8)));
typedef float  f32x4  __attribute__((ext_vector_type(4)));

#define B_   2
#define T_   2048
#define E_   1024
#define H_   16
#define D_   64
#define FF_  4096
#define NROW (B_ * T_)   // 4096
#define QS_  (3 * E_)    // packed QKV row stride
#define NTI  (T_ / 64)   // 32 q-tiles

__device__ __forceinline__ float4 ld4h(const f16_t* p)
{
    union { ushort4 u; f16_t h[4]; } c;
    c.u = *(const ushort4*)p;
    return make_float4((float)c.h[0], (float)c.h[1], (float)c.h[2], (float)c.h[3]);
}

// ---------------------------------------------------------------- LN ----
__global__ __launch_bounds__(256) void ln_kernel(
    const float* __restrict__ x, const float* __restrict__ g,
    const float* __restrict__ bta, bf16_t* __restrict__ out)
{
    int row = blockIdx.x;
    int tid = threadIdx.x;
    const float4* xr = (const float4*)(x + (size_t)row * E_);
    float4 v = xr[tid];
    float s  = v.x + v.y + v.z + v.w;
    float ss = v.x * v.x + v.y * v.y + v.z * v.z + v.w * v.w;
#pragma unroll
    for (int off = 32; off; off >>= 1) {
        s  += __shfl_xor(s, off);
        ss += __shfl_xor(ss, off);
    }
    __shared__ float red[8];
    int wave = tid >> 6, lane = tid & 63;
    if (lane == 0) { red[wave] = s; red[4 + wave] = ss; }
    __syncthreads();
    s  = red[0] + red[1] + red[2] + red[3];
    ss = red[4] + red[5] + red[6] + red[7];
    float mu   = s * (1.0f / E_);
    float var  = ss * (1.0f / E_) - mu * mu;
    float rstd = rsqrtf(var + 1e-5f);
    float4 gv = ((const float4*)g)[tid];
    float4 bv = ((const float4*)bta)[tid];
    union { bf16_t h[4]; ushort4 u; } pk;
    pk.h[0] = (bf16_t)((v.x - mu) * rstd * gv.x + bv.x);
    pk.h[1] = (bf16_t)((v.y - mu) * rstd * gv.y + bv.y);
    pk.h[2] = (bf16_t)((v.z - mu) * rstd * gv.z + bv.z);
    pk.h[3] = (bf16_t)((v.w - mu) * rstd * gv.w + bv.w);
    ((ushort4*)(out + (size_t)row * E_))[tid] = pk.u;
}

// ---------- split-K reduce (2 fp16 slices) + bias + resid + LN ---------
__global__ __launch_bounds__(256) void ln_reduce2(
    const f16_t* __restrict__ p, const float* __restrict__ bias,
    const float* __restrict__ resid, float* __restrict__ x1,
    const float* __restrict__ g, const float* __restrict__ bta,
    bf16_t* __restrict__ out)
{
    int row = blockIdx.x;
    int tid = threadIdx.x;
    size_t off = (size_t)row * E_;
    float4 v0 = ld4h(p + off + tid * 4);
    float4 v1 = ld4h(p + (size_t)NROW * E_ + off + tid * 4);
    float4 bb = ((const float4*)bias)[tid];
    float4 rr = ((const float4*)(resid + off))[tid];
    float4 v;
    v.x = v0.x + v1.x + bb.x + rr.x;
    v.y = v0.y + v1.y + bb.y + rr.y;
    v.z = v0.z + v1.z + bb.z + rr.z;
    v.w = v0.w + v1.w + bb.w + rr.w;
    ((float4*)(x1 + off))[tid] = v;
    float s  = v.x + v.y + v.z + v.w;
    float ss = v.x * v.x + v.y * v.y + v.z * v.z + v.w * v.w;
#pragma unroll
    for (int o = 32; o; o >>= 1) {
        s  += __shfl_xor(s, o);
        ss += __shfl_xor(ss, o);
    }
    __shared__ float red[8];
    int wave = tid >> 6, lane = tid & 63;
    if (lane == 0) { red[wave] = s; red[4 + wave] = ss; }
    __syncthreads();
    s  = red[0] + red[1] + red[2] + red[3];
    ss = red[4] + red[5] + red[6] + red[7];
    float mu   = s * (1.0f / E_);
    float var  = ss * (1.0f / E_) - mu * mu;
    float rstd = rsqrtf(var + 1e-5f);
    float4 gv = ((const float4*)g)[tid];
    float4 bv = ((const float4*)bta)[tid];
    union { bf16_t h[4]; ushort4 u; } pk;
    pk.h[0] = (bf16_t)((v.x - mu) * rstd * gv.x + bv.x);
    pk.h[1] = (bf16_t)((v.y - mu) * rstd * gv.y + bv.y);
    pk.h[2] = (bf16_t)((v.z - mu) * rstd * gv.z + bv.z);
    pk.h[3] = (bf16_t)((v.w - mu) * rstd * gv.w + bv.w);
    ((ushort4*)(out + off))[tid] = pk.u;
}

// ---------- split-K reduce (4 fp16 slices, contiguous) + bias + resid --
__global__ __launch_bounds__(256) void add_reduce4(
    const f16_t* __restrict__ p, const float* __restrict__ bias,
    const float* __restrict__ resid, float* __restrict__ out)
{
    int row = blockIdx.x;
    int tid = threadIdx.x;
    size_t off = (size_t)row * E_ + tid * 4;
    const size_t MN = (size_t)NROW * E_;
    float4 v0 = ld4h(p + off);
    float4 v1 = ld4h(p + MN + off);
    float4 v2 = ld4h(p + 2 * MN + off);
    float4 v3 = ld4h(p + 3 * MN + off);
    float4 bb = ((const float4*)bias)[tid];
    float4 rr = ((const float4*)(resid + (size_t)row * E_))[tid];
    float4 v;
    v.x = (v0.x + v1.x) + (v2.x + v3.x) + bb.x + rr.x;
    v.y = (v0.y + v1.y) + (v2.y + v3.y) + bb.y + rr.y;
    v.z = (v0.z + v1.z) + (v2.z + v3.z) + bb.z + rr.z;
    v.w = (v0.w + v1.w) + (v2.w + v3.w) + bb.w + rr.w;
    ((float4*)(out + (size_t)row * E_))[tid] = v;
}

// ------------------------- all weight transposes, one dispatch ----------
__global__ __launch_bounds__(256) void transpose_all(
    const float* __restrict__ Wq, const float* __restrict__ Wk,
    const float* __restrict__ Wv, const float* __restrict__ Wo,
    const float* __restrict__ W1, const float* __restrict__ W2,
    bf16_t* __restrict__ wqkv, bf16_t* __restrict__ wot,
    bf16_t* __restrict__ w1t, bf16_t* __restrict__ w2t)
{
    int l = blockIdx.x;
    const float* W; bf16_t* Wt; int K, N, bx, by;
    if (l < 4096) {
        int seg = l >> 10, r = l & 1023;
        K = E_; N = E_; bx = r & 31; by = r >> 5;
        if      (seg == 0) { W = Wq; Wt = wqkv; }
        else if (seg == 1) { W = Wk; Wt = wqkv + (size_t)E_ * E_; }
        else if (seg == 2) { W = Wv; Wt = wqkv + (size_t)2 * E_ * E_; }
        else               { W = Wo; Wt = wot; }
    } else if (l < 8192) {
        int r = l - 4096; K = E_; N = FF_; bx = r & 127; by = r >> 7;
        W = W1; Wt = w1t;
    } else {
        int r = l - 8192; K = FF_; N = E_; bx = r & 31; by = r >> 5;
        W = W2; Wt = w2t;
    }
    __shared__ float t[32][33];
    int n0 = bx * 32, k0 = by * 32;
    int tx = threadIdx.x & 31, ty = threadIdx.x >> 5;
#pragma unroll
    for (int i = 0; i < 4; ++i)
        t[ty + i * 8][tx] = W[(size_t)(k0 + ty + i * 8) * N + n0 + tx];
    __syncthreads();
#pragma unroll
    for (int i = 0; i < 4; ++i)
        Wt[(size_t)(n0 + ty + i * 8) * K + k0 + tx] = (bf16_t)t[tx][ty + i * 8];
}

__device__ __forceinline__ void gload16(const bf16_t* g, bf16_t* l)
{
    __builtin_amdgcn_global_load_lds(
        (const __attribute__((address_space(1))) void*)g,
        (__attribute__((address_space(3))) void*)l, 16, 0, 0);
}

// ------------------------------------------------- 128x128 GEMM (Wo) ----
// m97 structure + both-sides XOR swizzle + XCD-bijective block swizzle.
#define BM 128
#define BN 128
#define BK 64

__global__ __launch_bounds__(256) void gemm_bt(
    const bf16_t* __restrict__ A, const bf16_t* __restrict__ Bt,
    const float* __restrict__ bias, const float* __restrict__ resid,
    void* __restrict__ Cout, bf16_t* __restrict__ vt_out,
    int M, int N, int K, int lda, int ldb,
    int has_bias, int do_relu, int has_resid, int out_bf16)
{
    __shared__ __attribute__((aligned(16))) bf16_t As[BM * BK];
    __shared__ __attribute__((aligned(16))) bf16_t Bs[BN * BK];
    int tid  = threadIdx.x;
    int lane = tid & 63, wave = tid >> 6;
    // XCD-bijective remap (nwg multiple of 8)
    int gx = gridDim.x, nwg = gx * gridDim.y;
    int orig = blockIdx.y * gx + blockIdx.x;
    int wg = (orig & 7) * (nwg >> 3) + (orig >> 3);
    int m0 = (wg % gx) * BM, n0 = (wg / gx) * BN;
    int wm = (wave & 1) * 64, wn = (wave >> 1) * 64;
    int koff = blockIdx.z * K;
    f32x4 acc[4][4];
#pragma unroll
    for (int i = 0; i < 4; ++i)
#pragma unroll
        for (int j = 0; j < 4; ++j) acc[i][j] = (f32x4){0.f, 0.f, 0.f, 0.f};

    const int ml = lane & 15;
    const int g  = lane >> 4;
    const int swl = ml & 7;

    int r8 = lane >> 3;
    int scw = ((lane & 7) ^ r8) * 8;     // pre-swizzled source column
    const bf16_t* Ag = A  + (size_t)(m0 + wave * 32 + r8) * lda + koff + scw;
    const bf16_t* Bg = Bt + (size_t)(n0 + wave * 32 + r8) * ldb + koff + scw;
    bf16_t* Asw = &As[wave * 32 * BK];
    bf16_t* Bsw = &Bs[wave * 32 * BK];
    int niter = K / BK;

#pragma unroll
    for (int j = 0; j < 4; ++j) {
        gload16(Ag + (size_t)j * 8 * lda, Asw + j * 8 * BK);
        gload16(Bg + (size_t)j * 8 * ldb, Bsw + j * 8 * BK);
    }

    const char* Ac = (const char*)As;
    const char* Bc = (const char*)Bs;
    for (int it = 0; it < niter; ++it) {
        __syncthreads();
#pragma unroll
        for (int ks = 0; ks < 2; ++ks) {
            int swc = (((ks << 2) + g) ^ swl) << 4;
            bf16x8 af[4], bfr[4];
#pragma unroll
            for (int mi = 0; mi < 4; ++mi)
                af[mi] = *(const bf16x8*)(Ac + (wm + mi * 16 + ml) * 128 + swc);
#pragma unroll
            for (int ni = 0; ni < 4; ++ni)
                bfr[ni] = *(const bf16x8*)(Bc + (wn + ni * 16 + ml) * 128 + swc);
#pragma unroll
            for (int mi = 0; mi < 4; ++mi)
#pragma unroll
                for (int ni = 0; ni < 4; ++ni)
                    acc[mi][ni] = __builtin_amdgcn_mfma_f32_16x16x32_bf16(
                        af[mi], bfr[ni], acc[mi][ni], 0, 0, 0);
        }
        if (it + 1 < niter) {
            __syncthreads();
            int k0 = (it + 1) * BK;
#pragma unroll
            for (int j = 0; j < 4; ++j) {
                gload16(Ag + k0 + (size_t)j * 8 * lda, Asw + j * 8 * BK);
                gload16(Bg + k0 + (size_t)j * 8 * ldb, Bsw + j * 8 * BK);
            }
        }
    }

    int r4 = (lane >> 4) * 4;
    if (gridDim.z > 1) {
        f16_t* P = (f16_t*)Cout + (size_t)blockIdx.z * M * N;
#pragma unroll
        for (int mi = 0; mi < 4; ++mi)
#pragma unroll
            for (int ni = 0; ni < 4; ++ni) {
                int col = n0 + wn + ni * 16 + ml;
#pragma unroll
                for (int r = 0; r < 4; ++r) {
                    int row = m0 + wm + mi * 16 + r4 + r;
                    P[(size_t)row * N + col] = (f16_t)acc[mi][ni][r];
                }
            }
        return;
    }
#pragma unroll
    for (int mi = 0; mi < 4; ++mi) {
#pragma unroll
        for (int ni = 0; ni < 4; ++ni) {
            int col = n0 + wn + ni * 16 + ml;
            float bval = has_bias ? bias[col] : 0.0f;
#pragma unroll
            for (int r = 0; r < 4; ++r) {
                int row = m0 + wm + mi * 16 + r4 + r;
                float v = acc[mi][ni][r] + bval;
                if (do_relu)   v = fmaxf(v, 0.0f);
                if (has_resid) v += resid[(size_t)row * N + col];
                if (out_bf16)
                    ((bf16_t*)Cout)[(size_t)row * N + col] = (bf16_t)v;
                else
                    ((float*)Cout)[(size_t)row * N + col] = v;
            }
        }
    }
}

// --------------------- 256x256 8-phase GEMM (T1+T2+T3+T4+T5) ------------
__device__ __forceinline__ void g256_stage_half(
    const bf16_t* gbase, int ldg, bf16_t* lhalf, int wave, int lane)
{
    int r = lane >> 3, c = lane & 7;
    int sc = (c ^ r) * 8;
#pragma unroll
    for (int j = 0; j < 2; ++j) {
        const bf16_t* src = gbase + (size_t)(wave * 8 + j * 64 + r) * ldg + sc;
        bf16_t* dst = lhalf + (wave * 8 + j * 64) * 64;
        __builtin_amdgcn_global_load_lds(
            (const __attribute__((address_space(1))) void*)src,
            (__attribute__((address_space(3))) void*)dst, 16, 0, 0);
    }
}

__device__ __forceinline__ bf16x8 g256_frag(const bf16_t* half, int row, int kb)
{
    return *(const bf16x8*)((const char*)half + row * 128 + (kb ^ ((row & 7) << 4)));
}

template<int FP, bool DO_BFR>
__device__ __forceinline__ void g256_reads(
    const bf16_t* Ahx, const bf16_t* Bhx,
    bf16x8 (&af)[2][2], bf16x8 (&bfr)[4][2],
    int ml, int kq16, int brow0)
{
    if (DO_BFR) {
#pragma unroll
        for (int ni = 0; ni < 4; ++ni) {
            bfr[ni][0] = g256_frag(Bhx, brow0 + ni * 16 + ml, kq16);
            bfr[ni][1] = g256_frag(Bhx, brow0 + ni * 16 + ml, 64 + kq16);
        }
    }
#pragma unroll
    for (int i = 0; i < 2; ++i) {
        af[i][0] = g256_frag(Ahx, (2 * FP + i) * 16 + ml, kq16);
        af[i][1] = g256_frag(Ahx, (2 * FP + i) * 16 + ml, 64 + kq16);
    }
}

template<int FP>
__device__ __forceinline__ void g256_mfma(
    const bf16x8 (&af)[2][2], const bf16x8 (&bfr)[4][2], f32x4 (&acc)[8][4])
{
    __builtin_amdgcn_s_setprio(1);
#pragma unroll
    for (int i = 0; i < 2; ++i)
#pragma unroll
        for (int ni = 0; ni < 4; ++ni)
#pragma unroll
            for (int ks = 0; ks < 2; ++ks)
                acc[2 * FP + i][ni] = __builtin_amdgcn_mfma_f32_16x16x32_bf16(
                    af[i][ks], bfr[ni][ks], acc[2 * FP + i][ni], 0, 0, 0);
    __builtin_amdgcn_s_setprio(0);
}

#define AHALF(t, h) (ldsr + ((((t) & 1) * 4 + (h)) * (128 * 64)))
#define BHALF(t, h) (ldsr + ((((t) & 1) * 4 + 2 + (h)) * (128 * 64)))
#define STG_A(t, h) g256_stage_half(Ab + (size_t)((h) * 128) * lda + (t) * 64, lda, AHALF(t, h), wave, lane)
#define STG_B(t, h) g256_stage_half(Bb + (size_t)((h) * 128) * ldb + (t) * 64, ldb, BHALF(t, h), wave, lane)
#define SBAR() __builtin_amdgcn_s_barrier()

__global__ __launch_bounds__(512, 2) void gemm256(
    const bf16_t* __restrict__ A, const bf16_t* __restrict__ Bt,
    const float* __restrict__ bias,
    void* __restrict__ Cout, bf16_t* __restrict__ vt_out,
    int M, int N, int K, int lda, int ldb,
    int has_bias, int do_relu, int split)
{
    extern __shared__ __attribute__((aligned(16))) bf16_t ldsr[];
    int tid = threadIdx.x, lane = tid & 63, wave = tid >> 6;
    // XCD-bijective remap (nwg multiple of 8)
    int gx = gridDim.x, nwg = gx * gridDim.y;
    int orig = blockIdx.y * gx + blockIdx.x;
    int wg = (orig & 7) * (nwg >> 3) + (orig >> 3);
    int m0 = (wg % gx) * 256, n0 = (wg / gx) * 256;
    int koff = blockIdx.z * K;
    int ml = lane & 15, kq16 = (lane >> 4) * 16, r4 = (lane >> 4) * 4;
    int wr = (wave >> 2) * 128, wc = (wave & 3) * 64;
    int brow0 = (wave & 1) * 64;

    const bf16_t* Ab = A  + (size_t)m0 * lda + koff;
    const bf16_t* Bb = Bt + (size_t)n0 * ldb + koff;

    const bf16_t* A0 = AHALF(0, wave >> 2);
    const bf16_t* A1 = AHALF(1, wave >> 2);
    const bf16_t* B0 = BHALF(0, (wave & 3) >> 1);
    const bf16_t* B1 = BHALF(1, (wave & 3) >> 1);

    f32x4 acc[8][4];
#pragma unroll
    for (int i = 0; i < 8; ++i)
#pragma unroll
        for (int j = 0; j < 4; ++j) acc[i][j] = (f32x4){0.f, 0.f, 0.f, 0.f};
    bf16x8 bfr[4][2];

    STG_B(0, 0); STG_B(0, 1);
    STG_A(0, 0); STG_A(0, 1);
    STG_B(1, 0); STG_B(1, 1);
    asm volatile("s_waitcnt vmcnt(4)" ::: "memory");
    SBAR();

    int NIT2 = K / 128;
    for (int it = 0; it < NIT2; ++it) {
        bool last = (it == NIT2 - 1);
        int t1 = 2 * it + 1, t2 = 2 * it + 2, t3 = 2 * it + 3;
        bf16x8 af[2][2];

        g256_reads<0, true>(A0, B0, af, bfr, ml, kq16, brow0);
        STG_A(t1, 0);
        SBAR();
        g256_mfma<0>(af, bfr, acc);
        SBAR();

        g256_reads<1, false>(A0, B0, af, bfr, ml, kq16, brow0);
        STG_A(t1, 1);
        SBAR();
        g256_mfma<1>(af, bfr, acc);
        SBAR();

        g256_reads<2, false>(A0, B0, af, bfr, ml, kq16, brow0);
        if (!last) STG_B(t2, 0);
        SBAR();
        g256_mfma<2>(af, bfr, acc);
        SBAR();

        g256_reads<3, false>(A0, B0, af, bfr, ml, kq16, brow0);
        if (!last) STG_B(t2, 1);
        SBAR();
        g256_mfma<3>(af, bfr, acc);
        if (last) asm volatile("s_waitcnt vmcnt(0)" ::: "memory");
        else      asm volatile("s_waitcnt vmcnt(4)" ::: "memory");
        SBAR();

        g256_reads<0, true>(A1, B1, af, bfr, ml, kq16, brow0);
        if (!last) STG_A(t2, 0);
        SBAR();
        g256_mfma<0>(af, bfr, acc);
        SBAR();

        g256_reads<1, false>(A1, B1, af, bfr, ml, kq16, brow0);
        if (!last) STG_A(t2, 1);
        SBAR();
        g256_mfma<1>(af, bfr, acc);
        SBAR();

        g256_reads<2, false>(A1, B1, af, bfr, ml, kq16, brow0);
        if (!last) STG_B(t3, 0);
        SBAR();
        g256_mfma<2>(af, bfr, acc);
        SBAR();

        g256_reads<3, false>(A1, B1, af, bfr, ml, kq16, brow0);
        if (!last) STG_B(t3, 1);
        SBAR();
        g256_mfma<3>(af, bfr, acc);
        if (!last) asm volatile("s_waitcnt vmcnt(4)" ::: "memory");
        SBAR();
    }

    if (split > 1) {
        f16_t* P = (f16_t*)Cout + (size_t)blockIdx.z * M * N;
#pragma unroll
        for (int mi = 0; mi < 8; ++mi)
#pragma unroll
            for (int ni = 0; ni < 4; ++ni) {
                int col = n0 + wc + ni * 16 + ml;
#pragma unroll
                for (int r = 0; r < 4; ++r) {
                    int row = m0 + wr + mi * 16 + r4 + r;
                    P[(size_t)row * N + col] = (f16_t)acc[mi][ni][r];
                }
            }
        return;
    }
    if (vt_out && n0 >= 2 * E_) {
#pragma unroll
        for (int mi = 0; mi < 8; ++mi)
#pragma unroll
            for (int ni = 0; ni < 4; ++ni) {
                int vcol = n0 + wc + ni * 16 + ml - 2 * E_;
                int h = vcol >> 6, d = vcol & 63;
                int row0 = m0 + wr + mi * 16 + r4;
                int b = row0 >> 11, t = row0 & (T_ - 1);
                union { bf16_t h4[4]; uint2 u; } pk;
#pragma unroll
                for (int r = 0; r < 4; ++r) pk.h4[r] = (bf16_t)acc[mi][ni][r];
                *(uint2*)&vt_out[((size_t)(b * H_ + h) * D_ + d) * T_ + t] = pk.u;
            }
        return;
    }
#pragma unroll
    for (int mi = 0; mi < 8; ++mi) {
#pragma unroll
        for (int ni = 0; ni < 4; ++ni) {
            int col = n0 + wc + ni * 16 + ml;
            float bval = has_bias ? bias[col] : 0.0f;
#pragma unroll
            for (int r = 0; r < 4; ++r) {
                int row = m0 + wr + mi * 16 + r4 + r;
                float v = acc[mi][ni][r] + bval;
                if (do_relu) v = fmaxf(v, 0.0f);
                ((bf16_t*)Cout)[(size_t)row * N + col] = (bf16_t)v;
            }
        }
    }
}

// ------------------------------------------------- MFMA flash attention -
// 4 waves x dual-update: each wave owns 32 q-rows (two 16-row sub-tiles)
// and reads the shared K/V fragments ONCE per chunk (kf/vf have no wave
// dependence -> sharing halves the dominant LDS fragment-read traffic).
// Waves 0-1: hi q-tile; waves 2-3: lo q-tile.
// K/V: [64][64] bf16 LINEAR via global_load_lds, both-sides XOR swizzle.
// Fixed-base softmax in log2 domain (no running max, no in-loop shuffles).
#define PSTR 72
#define QSCL 0.1803368801111204f   // 0.125 * log2(e)

__device__ __forceinline__ float exp2_hw(float x)
{
    float r;
    asm("v_exp_f32 %0, %1" : "=v"(r) : "v"(x));
    return r;
}

struct TileState {
    f32x4 acc[4];
    float l1;
};

__device__ __forceinline__ void attn_stage4(
    const bf16_t* kb, const bf16_t* vb,
    bf16_t* ksl, bf16_t* vsl, int wave, int lane)
{
    int r = lane >> 3;
    int sc = ((lane & 7) ^ r) * 8;
    int rb = wave * 16;
    gload16(kb + (size_t)(rb + r) * QS_ + sc,     ksl + rb * 64);
    gload16(kb + (size_t)(rb + 8 + r) * QS_ + sc, ksl + (rb + 8) * 64);
    gload16(vb + (size_t)(rb + r) * T_ + sc,      vsl + rb * 64);
    gload16(vb + (size_t)(rb + 8 + r) * T_ + sc,  vsl + (rb + 8) * 64);
}

__device__ __forceinline__ void tile_update(
    const bf16x8 kf[2][4], const bf16x8 vf[2][4], const bf16x8 qf[2],
    TileState& st, bf16_t* PsW, int ml, int r4, int kq8,
    bool diag, int ch, int qrow)
{
    f32x4 s[4];
    __builtin_amdgcn_s_setprio(1);
#pragma unroll
    for (int nt = 0; nt < 4; ++nt) {
        s[nt] = (f32x4){0.f, 0.f, 0.f, 0.f};
#pragma unroll
        for (int ks = 0; ks < 2; ++ks)
            s[nt] = __builtin_amdgcn_mfma_f32_16x16x32_bf16(kf[ks][nt], qf[ks], s[nt], 0, 0, 0);
    }
    __builtin_amdgcn_s_setprio(0);
    if (diag) {
#pragma unroll
        for (int nt = 0; nt < 4; ++nt)
#pragma unroll
            for (int r = 0; r < 4; ++r)
                if (ch * 64 + nt * 16 + r4 + r > qrow) s[nt][r] = -INFINITY;
    }
    float sum = 0.f;
#pragma unroll
    for (int nt = 0; nt < 4; ++nt)
#pragma unroll
        for (int r = 0; r < 4; ++r) {
            float p = exp2_hw(s[nt][r]);
            s[nt][r] = p;
            sum += p;
        }
    st.l1 += sum;

#pragma unroll
    for (int nt = 0; nt < 4; ++nt) {
        union { bf16_t h[4]; uint2 u; } pk;
#pragma unroll
        for (int r = 0; r < 4; ++r) pk.h[r] = (bf16_t)s[nt][r];
        *(uint2*)&PsW[ml * PSTR + nt * 16 + r4] = pk.u;
    }
    __builtin_amdgcn_s_setprio(1);
#pragma unroll
    for (int ks = 0; ks < 2; ++ks) {
        bf16x8 pf = *(const bf16x8*)&PsW[ml * PSTR + ks * 32 + kq8];
#pragma unroll
        for (int dt = 0; dt < 4; ++dt)
            st.acc[dt] = __builtin_amdgcn_mfma_f32_16x16x32_bf16(vf[ks][dt], pf, st.acc[dt], 0, 0, 0);
    }
    __builtin_amdgcn_s_setprio(0);
}

__global__ __launch_bounds__(256) void attn_mfma(
    const bf16_t* __restrict__ Qp, const bf16_t* __restrict__ Kp,
    const bf16_t* __restrict__ Vt, bf16_t* __restrict__ O)
{
    __shared__ __attribute__((aligned(16))) bf16_t Ks[2][64 * 64];
    __shared__ __attribute__((aligned(16))) bf16_t Vts[2][64 * 64];
    __shared__ __attribute__((aligned(16))) bf16_t Ps[8][16 * PSTR];

    int tid = threadIdx.x, lane = tid & 63, wave = tid >> 6;   // wave 0-3
    int ml  = lane & 15;
    int kq8 = (lane >> 4) * 8;
    int g   = lane >> 4;
    int r4  = (lane >> 4) * 4;
    int swl = ml & 7;
    int bh = blockIdx.y, b = bh >> 4, h = bh & 15;
    size_t qk_base = (size_t)b * T_ * QS_ + h * D_;
    size_t vt_base = (size_t)bh * D_ * T_;
    size_t o_base  = (size_t)b * T_ * E_ + h * D_;

    int lo = blockIdx.x, hi = NTI - 1 - blockIdx.x;
    int half = wave >> 1, sub = wave & 1;
    int qtile = half ? lo : hi;
    int qw0 = qtile * 64 + sub * 32;   // this wave's rows [qw0, qw0+32)

    bf16x8 qf0[2], qf1[2];
#pragma unroll
    for (int ks = 0; ks < 2; ++ks) {
        bf16x8 a = *(const bf16x8*)&Qp[qk_base + (size_t)(qw0 + ml) * QS_ + ks * 32 + kq8];
        bf16x8 c = *(const bf16x8*)&Qp[qk_base + (size_t)(qw0 + 16 + ml) * QS_ + ks * 32 + kq8];
#pragma unroll
        for (int j = 0; j < 8; ++j) {
            a[j] = (bf16_t)((float)a[j] * QSCL);
            c[j] = (bf16_t)((float)c[j] * QSCL);
        }
        qf0[ks] = a; qf1[ks] = c;
    }

    TileState st0, st1;
#pragma unroll
    for (int dt = 0; dt < 4; ++dt) {
        st0.acc[dt] = (f32x4){0.f, 0.f, 0.f, 0.f};
        st1.acc[dt] = (f32x4){0.f, 0.f, 0.f, 0.f};
    }
    st0.l1 = 0.f; st1.l1 = 0.f;

    int nch = hi + 1;

    attn_stage4(Kp + qk_base, Vt + vt_base, Ks[0], Vts[0], wave, lane);

    for (int ch = 0; ch < nch; ++ch) {
        int cur = ch & 1, nxt = cur ^ 1;
        __syncthreads();

        if (ch + 1 < nch)
            attn_stage4(Kp + qk_base + (size_t)((ch + 1) * 64) * QS_,
                        Vt + vt_base + (ch + 1) * 64,
                        Ks[nxt], Vts[nxt], wave, lane);

        if (ch <= qtile) {
            bf16x8 kf[2][4], vf[2][4];
            const char* kc = (const char*)Ks[cur];
            const char* vc = (const char*)Vts[cur];
#pragma unroll
            for (int ks = 0; ks < 2; ++ks) {
                int swc = (((ks << 2) + g) ^ swl) << 4;
#pragma unroll
                for (int nt = 0; nt < 4; ++nt) {
                    int off = (nt * 16 + ml) * 128 + swc;
                    kf[ks][nt] = *(const bf16x8*)(kc + off);
                    vf[ks][nt] = *(const bf16x8*)(vc + off);
                }
            }
            bool dg = (ch == qtile);
            tile_update(kf, vf, qf0, st0, Ps[2 * wave], ml, r4, kq8,
                        dg, ch, qw0 + ml);
            tile_update(kf, vf, qf1, st1, Ps[2 * wave + 1], ml, r4, kq8,
                        dg, ch, qw0 + 16 + ml);
        }
    }

#pragma unroll
    for (int t = 0; t < 2; ++t) {
        TileState& st = t ? st1 : st0;
        int qwt = qw0 + t * 16;
        bf16_t* PsW = Ps[2 * wave + t];
        float l1 = st.l1;
        l1 += __shfl_xor(l1, 16);
        l1 += __shfl_xor(l1, 32);
        float inv = 1.0f / l1;
#pragma unroll
        for (int dt = 0; dt < 4; ++dt) {
            union { bf16_t h[4]; uint2 u; } pk;
#pragma unroll
            for (int r = 0; r < 4; ++r) pk.h[r] = (bf16_t)(st.acc[dt][r] * inv);
            *(uint2*)&PsW[ml * PSTR + dt * 16 + r4] = pk.u;
        }
        int row = lane >> 2, seg = (lane & 3) * 16;
        bf16x8 o0 = *(const bf16x8*)&PsW[row * PSTR + seg];
        bf16x8 o1 = *(const bf16x8*)&PsW[row * PSTR + seg + 8];
        size_t gp = o_base + (size_t)(qwt + row) * E_ + seg;
        *(bf16x8*)&O[gp]     = o0;
        *(bf16x8*)&O[gp + 8] = o1;
    }
}

// ------------------------------------------------------------ launch ---
extern "C" void kernel_launch(void* const* d_in, const int* in_sizes, int n_in,
                              void* d_out, int out_size, void* d_ws, size_t ws_size,
                              hipStream_t stream)
{
    const float* x    = (const float*)d_in[0];
    const float* ln1g = (const float*)d_in[1];
    const float* ln1b = (const float*)d_in[2];
    const float* Wq   = (const float*)d_in[3];
    const float* Wk   = (const float*)d_in[4];
    const float* Wv   = (const float*)d_in[5];
    const float* Wo   = (const float*)d_in[6];
    const float* bo   = (const float*)d_in[7];
    const float* ln2g = (const float*)d_in[8];
    const float* ln2b = (const float*)d_in[9];
    const float* W1   = (const float*)d_in[10];
    const float* b1   = (const float*)d_in[11];
    const float* W2   = (const float*)d_in[12];
    const float* b2   = (const float*)d_in[13];

    // Workspace map (MB), liveness-checked; peak 120 MB:
    //   0-8   w2t            (live to down-gemm)
    //   8-24  x1             (ln_reduce2 -> add_reduce4)
    //  24-56  part_wo fp16 (24-40, Wo-gemm -> ln_reduce2), then h1 (up -> down)
    //  56-64  w1t            (transpose -> up), then part4[0..]
    //  64-72  xn (ln1 -> qkv), then hb (ln_reduce2 -> up), then part4
    //  72-78  wqkv           (dead after qkv-gemm)
    //  78-80  wot            (dead after Wo-gemm)
    //  80-104 QKV            (dead after attn)
    // 104-112 Vtb            (dead after attn)
    // 112-120 att            (dead after Wo-gemm)
    //  56-88  part4 (4 x 8 MB fp16 split-K partials, contiguous; written
    //          by down-gemm when QKV region 80-88 is already dead)
    char* ws = (char*)d_ws;
    const size_t MB = 1024ull * 1024ull;
    bf16_t* w2t     = (bf16_t*)(ws + 0 * MB);
    float*  x1      = (float*)(ws + 8 * MB);
    f16_t*  part_wo = (f16_t*)(ws + 24 * MB);
    bf16_t* h1      = (bf16_t*)(ws + 24 * MB);
    bf16_t* w1t     = (bf16_t*)(ws + 56 * MB);
    bf16_t* xn      = (bf16_t*)(ws + 64 * MB);
    bf16_t* hb      = (bf16_t*)(ws + 64 * MB);
    bf16_t* wqkv    = (bf16_t*)(ws + 72 * MB);
    bf16_t* wot     = (bf16_t*)(ws + 78 * MB);
    bf16_t* QKV     = (bf16_t*)(ws + 80 * MB);
    bf16_t* Vtb     = (bf16_t*)(ws + 104 * MB);
    bf16_t* att     = (bf16_t*)(ws + 112 * MB);
    f16_t*  part4   = (f16_t*)(ws + 56 * MB);

    dim3 blk(256), blk5(512);
    const size_t LDS256 = 8 * 128 * 64 * sizeof(bf16_t);   // 128 KiB

    transpose_all<<<dim3(12288), blk, 0, stream>>>(
        Wq, Wk, Wv, Wo, W1, W2, wqkv, wot, w1t, w2t);

    ln_kernel<<<dim3(NROW), blk, 0, stream>>>(x, ln1g, ln1b, xn);

    // fused QKV projection; V slab written transposed per-head into Vtb
    gemm256<<<dim3(NROW / 256, QS_ / 256, 1), blk5, LDS256, stream>>>(
        xn, wqkv, nullptr, QKV, Vtb, NROW, QS_, E_, E_, E_, 0, 0, 1);

    attn_mfma<<<dim3(NTI / 2, B_ * H_), blk, 0, stream>>>(
        QKV, QKV + E_, Vtb, att);

    // Wo projection: split-K x2 fp16 partials -> reduce + LN2 fused
    gemm_bt<<<dim3(NROW / BM, E_ / BN, 2), blk, 0, stream>>>(
        att, wot, nullptr, nullptr, part_wo, nullptr, NROW, E_, E_ / 2, E_, E_, 0, 0, 0, 0);
    ln_reduce2<<<dim3(NROW), blk, 0, stream>>>(
        part_wo, bo, x, x1, ln2g, ln2b, hb);

    // MLP up + bias + relu
    gemm256<<<dim3(NROW / 256, FF_ / 256, 1), blk5, LDS256, stream>>>(
        hb, w1t, b1, h1, nullptr, NROW, FF_, E_, E_, E_, 1, 1, 1);

    // MLP down: split-K x4 fp16 partials -> reduce + b2 + resid
    gemm256<<<dim3(NROW / 256, E_ / 256, 4), blk5, LDS256, stream>>>(
        h1, w2t, nullptr, part4, nullptr, NROW, E_, FF_ / 4, FF_, FF_, 0, 0, 4);
    add_reduce4<<<dim3(NROW), blk, 0, stream>>>(
        part4, b2, x1, (float*)d_out);
}

// Round 8
// 308.868 us; speedup vs baseline: 1.0562x; 1.0562x over previous
//
#include <hip/hip_runtime.h>
#include <cmath>
#include <cstdint>
#include <cstddef>

typedef __bf16 bf16_t;
typedef _Float16 f16_t;
typedef __bf16 bf16x8 __attribute__((ext_vector_type(8)));
typedef float  f32x4  __attribute__((ext_vector_type(4)));

#define B_   2
#define T_   2048
#define E_   1024
#define H_   16
#define D_   64
#define FF_  4096
#define NROW (B_ * T_)   // 4096
#define QS_  (3 * E_)    // packed QKV row stride
#define NTI  (T_ / 64)   // 32 q-tiles

__device__ __forceinline__ float4 ld4h(const f16_t* p)
{
    union { ushort4 u; f16_t h[4]; } c;
    c.u = *(const ushort4*)p;
    return make_float4((float)c.h[0], (float)c.h[1], (float)c.h[2], (float)c.h[3]);
}

// ---------------- prep: all weight transposes + LN1, ONE dispatch -------
// Blocks [0,12288): W transposes (fp32 -> bf16, B^T layout).
// Blocks [12288,16384): LayerNorm(x) -> xn bf16. Independent work; merged
// so the BW-bound transpose and the small LN overlap on the CUs instead of
// running serially as two dispatches.
__global__ __launch_bounds__(256) void prep_kernel(
    const float* __restrict__ x, const float* __restrict__ g,
    const float* __restrict__ bta, bf16_t* __restrict__ xn,
    const float* __restrict__ Wq, const float* __restrict__ Wk,
    const float* __restrict__ Wv, const float* __restrict__ Wo,
    const float* __restrict__ W1, const float* __restrict__ W2,
    bf16_t* __restrict__ wqkv, bf16_t* __restrict__ wot,
    bf16_t* __restrict__ w1t, bf16_t* __restrict__ w2t)
{
    __shared__ float shbuf[32 * 33];
    int l = blockIdx.x;
    int tid = threadIdx.x;

    if (l >= 12288) {
        // ------------------------- LN path -------------------------
        int row = l - 12288;
        const float4* xr = (const float4*)(x + (size_t)row * E_);
        float4 v = xr[tid];
        float s  = v.x + v.y + v.z + v.w;
        float ss = v.x * v.x + v.y * v.y + v.z * v.z + v.w * v.w;
#pragma unroll
        for (int off = 32; off; off >>= 1) {
            s  += __shfl_xor(s, off);
            ss += __shfl_xor(ss, off);
        }
        int wave = tid >> 6, lane = tid & 63;
        if (lane == 0) { shbuf[wave] = s; shbuf[4 + wave] = ss; }
        __syncthreads();
        s  = shbuf[0] + shbuf[1] + shbuf[2] + shbuf[3];
        ss = shbuf[4] + shbuf[5] + shbuf[6] + shbuf[7];
        float mu   = s * (1.0f / E_);
        float var  = ss * (1.0f / E_) - mu * mu;
        float rstd = rsqrtf(var + 1e-5f);
        float4 gv = ((const float4*)g)[tid];
        float4 bv = ((const float4*)bta)[tid];
        union { bf16_t h[4]; ushort4 u; } pk;
        pk.h[0] = (bf16_t)((v.x - mu) * rstd * gv.x + bv.x);
        pk.h[1] = (bf16_t)((v.y - mu) * rstd * gv.y + bv.y);
        pk.h[2] = (bf16_t)((v.z - mu) * rstd * gv.z + bv.z);
        pk.h[3] = (bf16_t)((v.w - mu) * rstd * gv.w + bv.w);
        ((ushort4*)(xn + (size_t)row * E_))[tid] = pk.u;
        return;
    }

    // --------------------------- transpose path ---------------------------
    const float* W; bf16_t* Wt; int K, N, bx, by;
    if (l < 4096) {
        int seg = l >> 10, r = l & 1023;
        K = E_; N = E_; bx = r & 31; by = r >> 5;
        if      (seg == 0) { W = Wq; Wt = wqkv; }
        else if (seg == 1) { W = Wk; Wt = wqkv + (size_t)E_ * E_; }
        else if (seg == 2) { W = Wv; Wt = wqkv + (size_t)2 * E_ * E_; }
        else               { W = Wo; Wt = wot; }
    } else if (l < 8192) {
        int r = l - 4096; K = E_; N = FF_; bx = r & 127; by = r >> 7;
        W = W1; Wt = w1t;
    } else {
        int r = l - 8192; K = FF_; N = E_; bx = r & 31; by = r >> 5;
        W = W2; Wt = w2t;
    }
    int n0 = bx * 32, k0 = by * 32;
    int tx = tid & 31, ty = tid >> 5;
#pragma unroll
    for (int i = 0; i < 4; ++i)
        shbuf[(ty + i * 8) * 33 + tx] = W[(size_t)(k0 + ty + i * 8) * N + n0 + tx];
    __syncthreads();
#pragma unroll
    for (int i = 0; i < 4; ++i)
        Wt[(size_t)(n0 + ty + i * 8) * K + k0 + tx] = (bf16_t)shbuf[tx * 33 + ty + i * 8];
}

// ---------- split-K reduce (2 fp16 slices) + bias + resid + LN ---------
__global__ __launch_bounds__(256) void ln_reduce2(
    const f16_t* __restrict__ p, const float* __restrict__ bias,
    const float* __restrict__ resid, float* __restrict__ x1,
    const float* __restrict__ g, const float* __restrict__ bta,
    bf16_t* __restrict__ out)
{
    int row = blockIdx.x;
    int tid = threadIdx.x;
    size_t off = (size_t)row * E_;
    float4 v0 = ld4h(p + off + tid * 4);
    float4 v1 = ld4h(p + (size_t)NROW * E_ + off + tid * 4);
    float4 bb = ((const float4*)bias)[tid];
    float4 rr = ((const float4*)(resid + off))[tid];
    float4 v;
    v.x = v0.x + v1.x + bb.x + rr.x;
    v.y = v0.y + v1.y + bb.y + rr.y;
    v.z = v0.z + v1.z + bb.z + rr.z;
    v.w = v0.w + v1.w + bb.w + rr.w;
    ((float4*)(x1 + off))[tid] = v;
    float s  = v.x + v.y + v.z + v.w;
    float ss = v.x * v.x + v.y * v.y + v.z * v.z + v.w * v.w;
#pragma unroll
    for (int o = 32; o; o >>= 1) {
        s  += __shfl_xor(s, o);
        ss += __shfl_xor(ss, o);
    }
    __shared__ float red[8];
    int wave = tid >> 6, lane = tid & 63;
    if (lane == 0) { red[wave] = s; red[4 + wave] = ss; }
    __syncthreads();
    s  = red[0] + red[1] + red[2] + red[3];
    ss = red[4] + red[5] + red[6] + red[7];
    float mu   = s * (1.0f / E_);
    float var  = ss * (1.0f / E_) - mu * mu;
    float rstd = rsqrtf(var + 1e-5f);
    float4 gv = ((const float4*)g)[tid];
    float4 bv = ((const float4*)bta)[tid];
    union { bf16_t h[4]; ushort4 u; } pk;
    pk.h[0] = (bf16_t)((v.x - mu) * rstd * gv.x + bv.x);
    pk.h[1] = (bf16_t)((v.y - mu) * rstd * gv.y + bv.y);
    pk.h[2] = (bf16_t)((v.z - mu) * rstd * gv.z + bv.z);
    pk.h[3] = (bf16_t)((v.w - mu) * rstd * gv.w + bv.w);
    ((ushort4*)(out + off))[tid] = pk.u;
}

// ---------- split-K reduce (4 fp16 slices, contiguous) + bias + resid --
__global__ __launch_bounds__(256) void add_reduce4(
    const f16_t* __restrict__ p, const float* __restrict__ bias,
    const float* __restrict__ resid, float* __restrict__ out)
{
    int row = blockIdx.x;
    int tid = threadIdx.x;
    size_t off = (size_t)row * E_ + tid * 4;
    const size_t MN = (size_t)NROW * E_;
    float4 v0 = ld4h(p + off);
    float4 v1 = ld4h(p + MN + off);
    float4 v2 = ld4h(p + 2 * MN + off);
    float4 v3 = ld4h(p + 3 * MN + off);
    float4 bb = ((const float4*)bias)[tid];
    float4 rr = ((const float4*)(resid + (size_t)row * E_))[tid];
    float4 v;
    v.x = (v0.x + v1.x) + (v2.x + v3.x) + bb.x + rr.x;
    v.y = (v0.y + v1.y) + (v2.y + v3.y) + bb.y + rr.y;
    v.z = (v0.z + v1.z) + (v2.z + v3.z) + bb.z + rr.z;
    v.w = (v0.w + v1.w) + (v2.w + v3.w) + bb.w + rr.w;
    ((float4*)(out + (size_t)row * E_))[tid] = v;
}

__device__ __forceinline__ void gload16(const bf16_t* g, bf16_t* l)
{
    __builtin_amdgcn_global_load_lds(
        (const __attribute__((address_space(1))) void*)g,
        (__attribute__((address_space(3))) void*)l, 16, 0, 0);
}

// ------------------------------------------------- 128x128 GEMM (Wo) ----
// m97 structure + both-sides XOR swizzle + XCD-bijective block swizzle.
#define BM 128
#define BN 128
#define BK 64

__global__ __launch_bounds__(256) void gemm_bt(
    const bf16_t* __restrict__ A, const bf16_t* __restrict__ Bt,
    const float* __restrict__ bias, const float* __restrict__ resid,
    void* __restrict__ Cout, bf16_t* __restrict__ vt_out,
    int M, int N, int K, int lda, int ldb,
    int has_bias, int do_relu, int has_resid, int out_bf16)
{
    __shared__ __attribute__((aligned(16))) bf16_t As[BM * BK];
    __shared__ __attribute__((aligned(16))) bf16_t Bs[BN * BK];
    int tid  = threadIdx.x;
    int lane = tid & 63, wave = tid >> 6;
    // XCD-bijective remap (nwg multiple of 8)
    int gx = gridDim.x, nwg = gx * gridDim.y;
    int orig = blockIdx.y * gx + blockIdx.x;
    int wg = (orig & 7) * (nwg >> 3) + (orig >> 3);
    int m0 = (wg % gx) * BM, n0 = (wg / gx) * BN;
    int wm = (wave & 1) * 64, wn = (wave >> 1) * 64;
    int koff = blockIdx.z * K;
    f32x4 acc[4][4];
#pragma unroll
    for (int i = 0; i < 4; ++i)
#pragma unroll
        for (int j = 0; j < 4; ++j) acc[i][j] = (f32x4){0.f, 0.f, 0.f, 0.f};

    const int ml = lane & 15;
    const int g  = lane >> 4;
    const int swl = ml & 7;

    int r8 = lane >> 3;
    int scw = ((lane & 7) ^ r8) * 8;     // pre-swizzled source column
    const bf16_t* Ag = A  + (size_t)(m0 + wave * 32 + r8) * lda + koff + scw;
    const bf16_t* Bg = Bt + (size_t)(n0 + wave * 32 + r8) * ldb + koff + scw;
    bf16_t* Asw = &As[wave * 32 * BK];
    bf16_t* Bsw = &Bs[wave * 32 * BK];
    int niter = K / BK;

#pragma unroll
    for (int j = 0; j < 4; ++j) {
        gload16(Ag + (size_t)j * 8 * lda, Asw + j * 8 * BK);
        gload16(Bg + (size_t)j * 8 * ldb, Bsw + j * 8 * BK);
    }

    const char* Ac = (const char*)As;
    const char* Bc = (const char*)Bs;
    for (int it = 0; it < niter; ++it) {
        __syncthreads();
#pragma unroll
        for (int ks = 0; ks < 2; ++ks) {
            int swc = (((ks << 2) + g) ^ swl) << 4;
            bf16x8 af[4], bfr[4];
#pragma unroll
            for (int mi = 0; mi < 4; ++mi)
                af[mi] = *(const bf16x8*)(Ac + (wm + mi * 16 + ml) * 128 + swc);
#pragma unroll
            for (int ni = 0; ni < 4; ++ni)
                bfr[ni] = *(const bf16x8*)(Bc + (wn + ni * 16 + ml) * 128 + swc);
#pragma unroll
            for (int mi = 0; mi < 4; ++mi)
#pragma unroll
                for (int ni = 0; ni < 4; ++ni)
                    acc[mi][ni] = __builtin_amdgcn_mfma_f32_16x16x32_bf16(
                        af[mi], bfr[ni], acc[mi][ni], 0, 0, 0);
        }
        if (it + 1 < niter) {
            __syncthreads();
            int k0 = (it + 1) * BK;
#pragma unroll
            for (int j = 0; j < 4; ++j) {
                gload16(Ag + k0 + (size_t)j * 8 * lda, Asw + j * 8 * BK);
                gload16(Bg + k0 + (size_t)j * 8 * ldb, Bsw + j * 8 * BK);
            }
        }
    }

    int r4 = (lane >> 4) * 4;
    if (gridDim.z > 1) {
        f16_t* P = (f16_t*)Cout + (size_t)blockIdx.z * M * N;
#pragma unroll
        for (int mi = 0; mi < 4; ++mi)
#pragma unroll
            for (int ni = 0; ni < 4; ++ni) {
                int col = n0 + wn + ni * 16 + ml;
#pragma unroll
                for (int r = 0; r < 4; ++r) {
                    int row = m0 + wm + mi * 16 + r4 + r;
                    P[(size_t)row * N + col] = (f16_t)acc[mi][ni][r];
                }
            }
        return;
    }
#pragma unroll
    for (int mi = 0; mi < 4; ++mi) {
#pragma unroll
        for (int ni = 0; ni < 4; ++ni) {
            int col = n0 + wn + ni * 16 + ml;
            float bval = has_bias ? bias[col] : 0.0f;
#pragma unroll
            for (int r = 0; r < 4; ++r) {
                int row = m0 + wm + mi * 16 + r4 + r;
                float v = acc[mi][ni][r] + bval;
                if (do_relu)   v = fmaxf(v, 0.0f);
                if (has_resid) v += resid[(size_t)row * N + col];
                if (out_bf16)
                    ((bf16_t*)Cout)[(size_t)row * N + col] = (bf16_t)v;
                else
                    ((float*)Cout)[(size_t)row * N + col] = v;
            }
        }
    }
}

// --------------------- 256x256 8-phase GEMM (T1+T2+T3+T4+T5) ------------
__device__ __forceinline__ void g256_stage_half(
    const bf16_t* gbase, int ldg, bf16_t* lhalf, int wave, int lane)
{
    int r = lane >> 3, c = lane & 7;
    int sc = (c ^ r) * 8;
#pragma unroll
    for (int j = 0; j < 2; ++j) {
        const bf16_t* src = gbase + (size_t)(wave * 8 + j * 64 + r) * ldg + sc;
        bf16_t* dst = lhalf + (wave * 8 + j * 64) * 64;
        __builtin_amdgcn_global_load_lds(
            (const __attribute__((address_space(1))) void*)src,
            (__attribute__((address_space(3))) void*)dst, 16, 0, 0);
    }
}

__device__ __forceinline__ bf16x8 g256_frag(const bf16_t* half, int row, int kb)
{
    return *(const bf16x8*)((const char*)half + row * 128 + (kb ^ ((row & 7) << 4)));
}

template<int FP, bool DO_BFR>
__device__ __forceinline__ void g256_reads(
    const bf16_t* Ahx, const bf16_t* Bhx,
    bf16x8 (&af)[2][2], bf16x8 (&bfr)[4][2],
    int ml, int kq16, int brow0)
{
    if (DO_BFR) {
#pragma unroll
        for (int ni = 0; ni < 4; ++ni) {
            bfr[ni][0] = g256_frag(Bhx, brow0 + ni * 16 + ml, kq16);
            bfr[ni][1] = g256_frag(Bhx, brow0 + ni * 16 + ml, 64 + kq16);
        }
    }
#pragma unroll
    for (int i = 0; i < 2; ++i) {
        af[i][0] = g256_frag(Ahx, (2 * FP + i) * 16 + ml, kq16);
        af[i][1] = g256_frag(Ahx, (2 * FP + i) * 16 + ml, 64 + kq16);
    }
}

template<int FP>
__device__ __forceinline__ void g256_mfma(
    const bf16x8 (&af)[2][2], const bf16x8 (&bfr)[4][2], f32x4 (&acc)[8][4])
{
    __builtin_amdgcn_s_setprio(1);
#pragma unroll
    for (int i = 0; i < 2; ++i)
#pragma unroll
        for (int ni = 0; ni < 4; ++ni)
#pragma unroll
            for (int ks = 0; ks < 2; ++ks)
                acc[2 * FP + i][ni] = __builtin_amdgcn_mfma_f32_16x16x32_bf16(
                    af[i][ks], bfr[ni][ks], acc[2 * FP + i][ni], 0, 0, 0);
    __builtin_amdgcn_s_setprio(0);
}

#define AHALF(t, h) (ldsr + ((((t) & 1) * 4 + (h)) * (128 * 64)))
#define BHALF(t, h) (ldsr + ((((t) & 1) * 4 + 2 + (h)) * (128 * 64)))
#define STG_A(t, h) g256_stage_half(Ab + (size_t)((h) * 128) * lda + (t) * 64, lda, AHALF(t, h), wave, lane)
#define STG_B(t, h) g256_stage_half(Bb + (size_t)((h) * 128) * ldb + (t) * 64, ldb, BHALF(t, h), wave, lane)
#define SBAR() __builtin_amdgcn_s_barrier()

__global__ __launch_bounds__(512, 2) void gemm256(
    const bf16_t* __restrict__ A, const bf16_t* __restrict__ Bt,
    const float* __restrict__ bias,
    void* __restrict__ Cout, bf16_t* __restrict__ vt_out,
    int M, int N, int K, int lda, int ldb,
    int has_bias, int do_relu, int split)
{
    extern __shared__ __attribute__((aligned(16))) bf16_t ldsr[];
    int tid = threadIdx.x, lane = tid & 63, wave = tid >> 6;
    // XCD-bijective remap (nwg multiple of 8)
    int gx = gridDim.x, nwg = gx * gridDim.y;
    int orig = blockIdx.y * gx + blockIdx.x;
    int wg = (orig & 7) * (nwg >> 3) + (orig >> 3);
    int m0 = (wg % gx) * 256, n0 = (wg / gx) * 256;
    int koff = blockIdx.z * K;
    int ml = lane & 15, kq16 = (lane >> 4) * 16, r4 = (lane >> 4) * 4;
    int wr = (wave >> 2) * 128, wc = (wave & 3) * 64;
    int brow0 = (wave & 1) * 64;

    const bf16_t* Ab = A  + (size_t)m0 * lda + koff;
    const bf16_t* Bb = Bt + (size_t)n0 * ldb + koff;

    const bf16_t* A0 = AHALF(0, wave >> 2);
    const bf16_t* A1 = AHALF(1, wave >> 2);
    const bf16_t* B0 = BHALF(0, (wave & 3) >> 1);
    const bf16_t* B1 = BHALF(1, (wave & 3) >> 1);

    f32x4 acc[8][4];
#pragma unroll
    for (int i = 0; i < 8; ++i)
#pragma unroll
        for (int j = 0; j < 4; ++j) acc[i][j] = (f32x4){0.f, 0.f, 0.f, 0.f};
    bf16x8 bfr[4][2];

    STG_B(0, 0); STG_B(0, 1);
    STG_A(0, 0); STG_A(0, 1);
    STG_B(1, 0); STG_B(1, 1);
    asm volatile("s_waitcnt vmcnt(4)" ::: "memory");
    SBAR();

    int NIT2 = K / 128;
    for (int it = 0; it < NIT2; ++it) {
        bool last = (it == NIT2 - 1);
        int t1 = 2 * it + 1, t2 = 2 * it + 2, t3 = 2 * it + 3;
        bf16x8 af[2][2];

        g256_reads<0, true>(A0, B0, af, bfr, ml, kq16, brow0);
        STG_A(t1, 0);
        SBAR();
        g256_mfma<0>(af, bfr, acc);
        SBAR();

        g256_reads<1, false>(A0, B0, af, bfr, ml, kq16, brow0);
        STG_A(t1, 1);
        SBAR();
        g256_mfma<1>(af, bfr, acc);
        SBAR();

        g256_reads<2, false>(A0, B0, af, bfr, ml, kq16, brow0);
        if (!last) STG_B(t2, 0);
        SBAR();
        g256_mfma<2>(af, bfr, acc);
        SBAR();

        g256_reads<3, false>(A0, B0, af, bfr, ml, kq16, brow0);
        if (!last) STG_B(t2, 1);
        SBAR();
        g256_mfma<3>(af, bfr, acc);
        if (last) asm volatile("s_waitcnt vmcnt(0)" ::: "memory");
        else      asm volatile("s_waitcnt vmcnt(4)" ::: "memory");
        SBAR();

        g256_reads<0, true>(A1, B1, af, bfr, ml, kq16, brow0);
        if (!last) STG_A(t2, 0);
        SBAR();
        g256_mfma<0>(af, bfr, acc);
        SBAR();

        g256_reads<1, false>(A1, B1, af, bfr, ml, kq16, brow0);
        if (!last) STG_A(t2, 1);
        SBAR();
        g256_mfma<1>(af, bfr, acc);
        SBAR();

        g256_reads<2, false>(A1, B1, af, bfr, ml, kq16, brow0);
        if (!last) STG_B(t3, 0);
        SBAR();
        g256_mfma<2>(af, bfr, acc);
        SBAR();

        g256_reads<3, false>(A1, B1, af, bfr, ml, kq16, brow0);
        if (!last) STG_B(t3, 1);
        SBAR();
        g256_mfma<3>(af, bfr, acc);
        if (!last) asm volatile("s_waitcnt vmcnt(4)" ::: "memory");
        SBAR();
    }

    if (split > 1) {
        f16_t* P = (f16_t*)Cout + (size_t)blockIdx.z * M * N;
#pragma unroll
        for (int mi = 0; mi < 8; ++mi)
#pragma unroll
            for (int ni = 0; ni < 4; ++ni) {
                int col = n0 + wc + ni * 16 + ml;
#pragma unroll
                for (int r = 0; r < 4; ++r) {
                    int row = m0 + wr + mi * 16 + r4 + r;
                    P[(size_t)row * N + col] = (f16_t)acc[mi][ni][r];
                }
            }
        return;
    }
    if (vt_out && n0 >= 2 * E_) {
#pragma unroll
        for (int mi = 0; mi < 8; ++mi)
#pragma unroll
            for (int ni = 0; ni < 4; ++ni) {
                int vcol = n0 + wc + ni * 16 + ml - 2 * E_;
                int h = vcol >> 6, d = vcol & 63;
                int row0 = m0 + wr + mi * 16 + r4;
                int b = row0 >> 11, t = row0 & (T_ - 1);
                union { bf16_t h4[4]; uint2 u; } pk;
#pragma unroll
                for (int r = 0; r < 4; ++r) pk.h4[r] = (bf16_t)acc[mi][ni][r];
                *(uint2*)&vt_out[((size_t)(b * H_ + h) * D_ + d) * T_ + t] = pk.u;
            }
        return;
    }
#pragma unroll
    for (int mi = 0; mi < 8; ++mi) {
#pragma unroll
        for (int ni = 0; ni < 4; ++ni) {
            int col = n0 + wc + ni * 16 + ml;
            float bval = has_bias ? bias[col] : 0.0f;
#pragma unroll
            for (int r = 0; r < 4; ++r) {
                int row = m0 + wr + mi * 16 + r4 + r;
                float v = acc[mi][ni][r] + bval;
                if (do_relu) v = fmaxf(v, 0.0f);
                ((bf16_t*)Cout)[(size_t)row * N + col] = (bf16_t)v;
            }
        }
    }
}

// ------------------------------------------------- MFMA flash attention -
// Wave-split (8 waves: 0-3 hi tile, 4-7 lo tile), one update/wave/chunk.
// K/V: [64][64] bf16 LINEAR via global_load_lds, both-sides XOR swizzle.
// Fixed-base softmax in log2 domain (no running max, no in-loop shuffles).
// NOTE (r7 lesson): 4-wave dual-update (halved LDS reads) and 8-wave at
// higher occupancy both REGRESSED — this shape is the measured optimum.
#define PSTR 72
#define QSCL 0.1803368801111204f   // 0.125 * log2(e)

__device__ __forceinline__ float exp2_hw(float x)
{
    float r;
    asm("v_exp_f32 %0, %1" : "=v"(r) : "v"(x));
    return r;
}

struct TileState {
    f32x4 acc[4];
    float l1;
};

__device__ __forceinline__ void attn_stage8(
    const bf16_t* kb, const bf16_t* vb,
    bf16_t* ksl, bf16_t* vsl, int wave, int lane)
{
    int r = lane >> 3;
    int sc = ((lane & 7) ^ r) * 8;
    int rb = wave * 8;
    gload16(kb + (size_t)(rb + r) * QS_ + sc, ksl + rb * 64);
    gload16(vb + (size_t)(rb + r) * T_  + sc, vsl + rb * 64);
}

__device__ __forceinline__ void tile_update(
    const bf16x8 kf[2][4], const bf16x8 vf[2][4], const bf16x8 qf[2],
    TileState& st, bf16_t* PsW, int ml, int r4, int kq8,
    bool diag, int ch, int qrow)
{
    f32x4 s[4];
    __builtin_amdgcn_s_setprio(1);
#pragma unroll
    for (int nt = 0; nt < 4; ++nt) {
        s[nt] = (f32x4){0.f, 0.f, 0.f, 0.f};
#pragma unroll
        for (int ks = 0; ks < 2; ++ks)
            s[nt] = __builtin_amdgcn_mfma_f32_16x16x32_bf16(kf[ks][nt], qf[ks], s[nt], 0, 0, 0);
    }
    __builtin_amdgcn_s_setprio(0);
    if (diag) {
#pragma unroll
        for (int nt = 0; nt < 4; ++nt)
#pragma unroll
            for (int r = 0; r < 4; ++r)
                if (ch * 64 + nt * 16 + r4 + r > qrow) s[nt][r] = -INFINITY;
    }
    float sum = 0.f;
#pragma unroll
    for (int nt = 0; nt < 4; ++nt)
#pragma unroll
        for (int r = 0; r < 4; ++r) {
            float p = exp2_hw(s[nt][r]);
            s[nt][r] = p;
            sum += p;
        }
    st.l1 += sum;

#pragma unroll
    for (int nt = 0; nt < 4; ++nt) {
        union { bf16_t h[4]; uint2 u; } pk;
#pragma unroll
        for (int r = 0; r < 4; ++r) pk.h[r] = (bf16_t)s[nt][r];
        *(uint2*)&PsW[ml * PSTR + nt * 16 + r4] = pk.u;
    }
    __builtin_amdgcn_s_setprio(1);
#pragma unroll
    for (int ks = 0; ks < 2; ++ks) {
        bf16x8 pf = *(const bf16x8*)&PsW[ml * PSTR + ks * 32 + kq8];
#pragma unroll
        for (int dt = 0; dt < 4; ++dt)
            st.acc[dt] = __builtin_amdgcn_mfma_f32_16x16x32_bf16(vf[ks][dt], pf, st.acc[dt], 0, 0, 0);
    }
    __builtin_amdgcn_s_setprio(0);
}

__global__ __launch_bounds__(512, 4) void attn_mfma(
    const bf16_t* __restrict__ Qp, const bf16_t* __restrict__ Kp,
    const bf16_t* __restrict__ Vt, bf16_t* __restrict__ O)
{
    __shared__ __attribute__((aligned(16))) bf16_t Ks[2][64 * 64];
    __shared__ __attribute__((aligned(16))) bf16_t Vts[2][64 * 64];
    __shared__ __attribute__((aligned(16))) bf16_t Ps[8][16 * PSTR];

    int tid = threadIdx.x, lane = tid & 63, wave = tid >> 6;
    int ml  = lane & 15;
    int kq8 = (lane >> 4) * 8;
    int g   = lane >> 4;
    int r4  = (lane >> 4) * 4;
    int swl = ml & 7;
    int bh = blockIdx.y, b = bh >> 4, h = bh & 15;
    size_t qk_base = (size_t)b * T_ * QS_ + h * D_;
    size_t vt_base = (size_t)bh * D_ * T_;
    size_t o_base  = (size_t)b * T_ * E_ + h * D_;

    int lo = blockIdx.x, hi = NTI - 1 - blockIdx.x;
    int half = wave >> 2, w4 = wave & 3;
    int qtile = half ? lo : hi;
    int qw = qtile * 64 + w4 * 16;

    bf16x8 qf[2];
#pragma unroll
    for (int ks = 0; ks < 2; ++ks) {
        bf16x8 a = *(const bf16x8*)&Qp[qk_base + (size_t)(qw + ml) * QS_ + ks * 32 + kq8];
#pragma unroll
        for (int j = 0; j < 8; ++j)
            a[j] = (bf16_t)((float)a[j] * QSCL);
        qf[ks] = a;
    }

    TileState st;
#pragma unroll
    for (int dt = 0; dt < 4; ++dt)
        st.acc[dt] = (f32x4){0.f, 0.f, 0.f, 0.f};
    st.l1 = 0.f;

    int nch = hi + 1;

    attn_stage8(Kp + qk_base, Vt + vt_base, Ks[0], Vts[0], wave, lane);

    for (int ch = 0; ch < nch; ++ch) {
        int cur = ch & 1, nxt = cur ^ 1;
        __syncthreads();

        if (ch + 1 < nch)
            attn_stage8(Kp + qk_base + (size_t)((ch + 1) * 64) * QS_,
                        Vt + vt_base + (ch + 1) * 64,
                        Ks[nxt], Vts[nxt], wave, lane);

        if (ch <= qtile) {
            bf16x8 kf[2][4], vf[2][4];
            const char* kc = (const char*)Ks[cur];
            const char* vc = (const char*)Vts[cur];
#pragma unroll
            for (int ks = 0; ks < 2; ++ks) {
                int swc = (((ks << 2) + g) ^ swl) << 4;
#pragma unroll
                for (int nt = 0; nt < 4; ++nt) {
                    int off = (nt * 16 + ml) * 128 + swc;
                    kf[ks][nt] = *(const bf16x8*)(kc + off);
                    vf[ks][nt] = *(const bf16x8*)(vc + off);
                }
            }
            tile_update(kf, vf, qf, st, Ps[wave], ml, r4, kq8,
                        ch == qtile, ch, qw + ml);
        }
    }

    {
        float l1 = st.l1;
        l1 += __shfl_xor(l1, 16);
        l1 += __shfl_xor(l1, 32);
        float inv = 1.0f / l1;
        bf16_t* PsW = Ps[wave];
#pragma unroll
        for (int dt = 0; dt < 4; ++dt) {
            union { bf16_t h[4]; uint2 u; } pk;
#pragma unroll
            for (int r = 0; r < 4; ++r) pk.h[r] = (bf16_t)(st.acc[dt][r] * inv);
            *(uint2*)&PsW[ml * PSTR + dt * 16 + r4] = pk.u;
        }
        int row = lane >> 2, seg = (lane & 3) * 16;
        bf16x8 o0 = *(const bf16x8*)&PsW[row * PSTR + seg];
        bf16x8 o1 = *(const bf16x8*)&PsW[row * PSTR + seg + 8];
        size_t gp = o_base + (size_t)(qw + row) * E_ + seg;
        *(bf16x8*)&O[gp]     = o0;
        *(bf16x8*)&O[gp + 8] = o1;
    }
}

// ------------------------------------------------------------ launch ---
extern "C" void kernel_launch(void* const* d_in, const int* in_sizes, int n_in,
                              void* d_out, int out_size, void* d_ws, size_t ws_size,
                              hipStream_t stream)
{
    const float* x    = (const float*)d_in[0];
    const float* ln1g = (const float*)d_in[1];
    const float* ln1b = (const float*)d_in[2];
    const float* Wq   = (const float*)d_in[3];
    const float* Wk   = (const float*)d_in[4];
    const float* Wv   = (const float*)d_in[5];
    const float* Wo   = (const float*)d_in[6];
    const float* bo   = (const float*)d_in[7];
    const float* ln2g = (const float*)d_in[8];
    const float* ln2b = (const float*)d_in[9];
    const float* W1   = (const float*)d_in[10];
    const float* b1   = (const float*)d_in[11];
    const float* W2   = (const float*)d_in[12];
    const float* b2   = (const float*)d_in[13];

    // Workspace map (MB), liveness-checked; peak 120 MB:
    //   0-8   w2t            (live to down-gemm)
    //   8-24  x1             (ln_reduce2 -> add_reduce4)
    //  24-56  part_wo fp16 (24-40, Wo-gemm -> ln_reduce2), then h1 (up -> down)
    //  56-64  w1t            (transpose -> up), then part4[0..]
    //  64-72  xn (prep -> qkv), then hb (ln_reduce2 -> up), then part4
    //  72-78  wqkv           (dead after qkv-gemm)
    //  78-80  wot            (dead after Wo-gemm)
    //  80-104 QKV            (dead after attn)
    // 104-112 Vtb            (dead after attn)
    // 112-120 att            (dead after Wo-gemm)
    //  56-88  part4 (4 x 8 MB fp16 split-K partials, contiguous; written
    //          by down-gemm when QKV region 80-88 is already dead)
    char* ws = (char*)d_ws;
    const size_t MB = 1024ull * 1024ull;
    bf16_t* w2t     = (bf16_t*)(ws + 0 * MB);
    float*  x1      = (float*)(ws + 8 * MB);
    f16_t*  part_wo = (f16_t*)(ws + 24 * MB);
    bf16_t* h1      = (bf16_t*)(ws + 24 * MB);
    bf16_t* w1t     = (bf16_t*)(ws + 56 * MB);
    bf16_t* xn      = (bf16_t*)(ws + 64 * MB);
    bf16_t* hb      = (bf16_t*)(ws + 64 * MB);
    bf16_t* wqkv    = (bf16_t*)(ws + 72 * MB);
    bf16_t* wot     = (bf16_t*)(ws + 78 * MB);
    bf16_t* QKV     = (bf16_t*)(ws + 80 * MB);
    bf16_t* Vtb     = (bf16_t*)(ws + 104 * MB);
    bf16_t* att     = (bf16_t*)(ws + 112 * MB);
    f16_t*  part4   = (f16_t*)(ws + 56 * MB);

    dim3 blk(256), blk5(512);
    const size_t LDS256 = 8 * 128 * 64 * sizeof(bf16_t);   // 128 KiB

    // prep: all weight transposes + LN1 in ONE dispatch (overlap on CUs)
    prep_kernel<<<dim3(12288 + NROW), blk, 0, stream>>>(
        x, ln1g, ln1b, xn, Wq, Wk, Wv, Wo, W1, W2, wqkv, wot, w1t, w2t);

    // fused QKV projection; V slab written transposed per-head into Vtb
    gemm256<<<dim3(NROW / 256, QS_ / 256, 1), blk5, LDS256, stream>>>(
        xn, wqkv, nullptr, QKV, Vtb, NROW, QS_, E_, E_, E_, 0, 0, 1);

    attn_mfma<<<dim3(NTI / 2, B_ * H_), dim3(512), 0, stream>>>(
        QKV, QKV + E_, Vtb, att);

    // Wo projection: split-K x2 fp16 partials -> reduce + LN2 fused
    gemm_bt<<<dim3(NROW / BM, E_ / BN, 2), blk, 0, stream>>>(
        att, wot, nullptr, nullptr, part_wo, nullptr, NROW, E_, E_ / 2, E_, E_, 0, 0, 0, 0);
    ln_reduce2<<<dim3(NROW), blk, 0, stream>>>(
        part_wo, bo, x, x1, ln2g, ln2b, hb);

    // MLP up + bias + relu
    gemm256<<<dim3(NROW / 256, FF_ / 256, 1), blk5, LDS256, stream>>>(
        hb, w1t, b1, h1, nullptr, NROW, FF_, E_, E_, E_, 1, 1, 1);

    // MLP down: split-K x4 fp16 partials -> reduce + b2 + resid
    gemm256<<<dim3(NROW / 256, E_ / 256, 4), blk5, LDS256, stream>>>(
        h1, w2t, nullptr, part4, nullptr, NROW, E_, FF_ / 4, FF_, FF_, 0, 0, 4);
    add_reduce4<<<dim3(NROW), blk, 0, stream>>>(
        part4, b2, x1, (float*)d_out);
}